// Round 1
// baseline (379.051 us; speedup 1.0000x reference)
//
#include <hip/hip_runtime.h>
#include <stdint.h>

#define B_ 8
#define N_ 2048
#define F_ 256

typedef unsigned short u16;
typedef __attribute__((ext_vector_type(8))) short bf16x8;   // 8 bf16 in 4 VGPRs
typedef __attribute__((ext_vector_type(4))) float f32x4;

// round-to-nearest-even f32 -> bf16
__device__ __forceinline__ u16 f2bf(float f) {
    uint32_t u = __builtin_bit_cast(uint32_t, f);
    u += 0x7FFFu + ((u >> 16) & 1u);
    return (u16)(u >> 16);
}

// async global->LDS, 16B per lane. LDS dest = wave-uniform base + lane*16.
__device__ __forceinline__ void gload_lds16(const void* g, void* lds_uniform_base) {
    __builtin_amdgcn_global_load_lds(
        (const __attribute__((address_space(1))) uint32_t*)g,
        (__attribute__((address_space(3))) uint32_t*)lds_uniform_base, 16, 0, 0);
}

// ---------------------------------------------------------------------------
// K1: degrees. deg_row[b,i] = sum_j adj[b,i,j]; deg_col[b,j] = sum_i adj[b,i,j]
// 16-row panels, thread t owns cols 8t..8t+7 (2x float4, coalesced).
// ---------------------------------------------------------------------------
__global__ __launch_bounds__(256) void k_deg(const float* __restrict__ adj,
                                             float* __restrict__ deg_row,
                                             float* __restrict__ deg_col) {
    const int b = blockIdx.y, panel = blockIdx.x;      // 128 panels x 16 rows
    const int t = threadIdx.x, w = t >> 6, l = t & 63;
    const float* base = adj + ((size_t)b * N_ + (size_t)panel * 16) * N_ + t * 8;
    float c[8];
#pragma unroll
    for (int e = 0; e < 8; ++e) c[e] = 0.f;
    __shared__ float rs[16][4];
#pragma unroll 4
    for (int r = 0; r < 16; ++r) {
        const float4 v0 = *(const float4*)(base + (size_t)r * N_);
        const float4 v1 = *(const float4*)(base + (size_t)r * N_ + 4);
        c[0] += v0.x; c[1] += v0.y; c[2] += v0.z; c[3] += v0.w;
        c[4] += v1.x; c[5] += v1.y; c[6] += v1.z; c[7] += v1.w;
        float s = (v0.x + v0.y) + (v0.z + v0.w) + (v1.x + v1.y) + (v1.z + v1.w);
#pragma unroll
        for (int off = 32; off; off >>= 1) s += __shfl_xor(s, off);
        if (l == 0) rs[r][w] = s;
    }
    float* dc = deg_col + (size_t)b * N_ + t * 8;
#pragma unroll
    for (int e = 0; e < 8; ++e) atomicAdd(dc + e, c[e]);
    __syncthreads();
    if (t < 16)
        deg_row[(size_t)b * N_ + panel * 16 + t] = rs[t][0] + rs[t][1] + rs[t][2] + rs[t][3];
}

// ---------------------------------------------------------------------------
// K2: LayerNorm -> xn (bf16 row-major [b][n][f]) and yT (bf16 [b][f][n]).
// 32-row panels; wave w handles 8 rows; transpose via padded LDS tile.
// ---------------------------------------------------------------------------
__global__ __launch_bounds__(256) void k_ln(const float* __restrict__ x,
                                            const float* __restrict__ gamma,
                                            const float* __restrict__ beta,
                                            const float* __restrict__ deg_row,
                                            u16* __restrict__ xn,
                                            u16* __restrict__ yT) {
    const int b = blockIdx.y, panel = blockIdx.x;      // 64 panels x 32 rows
    const int t = threadIdx.x, w = t >> 6, l = t & 63;
    __shared__ u16 yt[256 * 34];                       // [f][jj], pad 34 -> 2-way banks (free)
    float g[4], be[4];
#pragma unroll
    for (int m = 0; m < 4; ++m) { g[m] = gamma[l + 64 * m]; be[m] = beta[l + 64 * m]; }
    for (int rr = 0; rr < 8; ++rr) {
        const int jj = w * 8 + rr;
        const int j = panel * 32 + jj;
        const float* xp = x + ((size_t)b * N_ + j) * F_;
        float v[4], s = 0.f, ss = 0.f;
#pragma unroll
        for (int m = 0; m < 4; ++m) { v[m] = xp[l + 64 * m]; s += v[m]; ss += v[m] * v[m]; }
#pragma unroll
        for (int off = 32; off; off >>= 1) { s += __shfl_xor(s, off); ss += __shfl_xor(ss, off); }
        const float mu = s * (1.f / 256.f);
        const float var = ss * (1.f / 256.f) - mu * mu;
        const float rstd = rsqrtf(var + 1e-5f);
        const float d = deg_row[(size_t)b * N_ + j];
        const float sin_ = (d != 0.f) ? rsqrtf(d) : 0.f;
        u16* xnp = xn + ((size_t)b * N_ + j) * F_;
#pragma unroll
        for (int m = 0; m < 4; ++m) {
            const float xv = (v[m] - mu) * rstd * g[m] + be[m];
            xnp[l + 64 * m] = f2bf(xv);
            yt[(l + 64 * m) * 34 + jj] = f2bf(sin_ * xv);
        }
    }
    __syncthreads();
    // write yT: thread t -> f = (t>>1)+128*m2, 16-j chunk (t&1)
#pragma unroll
    for (int m2 = 0; m2 < 2; ++m2) {
        const int f = (t >> 1) + 128 * m2;
        const int jj0 = (t & 1) * 16;
        uint32_t vals[8];
#pragma unroll
        for (int e = 0; e < 8; ++e) vals[e] = *(const uint32_t*)&yt[f * 34 + jj0 + 2 * e];
        uint4* dst = (uint4*)(yT + ((size_t)b * F_ + f) * N_ + panel * 32 + jj0);
        dst[0] = make_uint4(vals[0], vals[1], vals[2], vals[3]);
        dst[1] = make_uint4(vals[4], vals[5], vals[6], vals[7]);
    }
}

// ---------------------------------------------------------------------------
// Kw: WcT[o][k] = bf16(Ws[k][o] + Wn[k][o]); WnT[o][k] = bf16(-Wn[k][o])
// ---------------------------------------------------------------------------
__global__ __launch_bounds__(256) void k_wprep(const float* __restrict__ Ws,
                                               const float* __restrict__ Wn,
                                               u16* __restrict__ WcT,
                                               u16* __restrict__ WnT) {
    const int k = blockIdx.x, o = threadIdx.x;
    const float a = Ws[k * 256 + o], q = Wn[k * 256 + o];
    WcT[o * 256 + k] = f2bf(a + q);
    WnT[o * 256 + k] = f2bf(-q);
}

// ---------------------------------------------------------------------------
// K3: z[b,i,f] = bf16( s_out[b,i] * sum_j adj[b,i,j] * yT[b,f,j] )
// 128x128 tile, BK=32, 512 threads (8 waves: 2 row x 4 col, each 64x32).
// A: fp32 reg-staged + cvt; B: global_load_lds width 16.
// Block->tile map keeps one batch per XCD (blockIdx%8 presumed XCD).
// ---------------------------------------------------------------------------
__global__ __launch_bounds__(512) void k_gemm1(const float* __restrict__ adj,
                                               const u16* __restrict__ yT,
                                               const float* __restrict__ deg_col,
                                               u16* __restrict__ z) {
    const int i = blockIdx.x;                 // 256 blocks
    const int g = i & 7, s = i >> 3;
    const int bm = g * 16 + (s & 15);         // 0..127 : batch-major m-tile
    const int nt = s >> 4;                    // 0..1
    const int b = bm >> 4, m = bm & 15;
    const int i0 = m * 128, f0 = nt * 128;
    const int t = threadIdx.x, w = t >> 6, l = t & 63;
    const int wr = w >> 2, wc = w & 3;        // wave -> 64x32 subtile
    alignas(16) __shared__ u16 As[128 * 32];  // [i][k] 8 KB
    alignas(16) __shared__ u16 Bs[128 * 32];  // [f][k] 8 KB
    f32x4 acc[4][2];
#pragma unroll
    for (int mi = 0; mi < 4; ++mi)
#pragma unroll
        for (int ni = 0; ni < 2; ++ni) acc[mi][ni] = (f32x4)0.f;

    const float* abase = adj + ((size_t)b * N_ + i0) * N_;
    const u16* ybase = yT + ((size_t)b * F_ + f0) * (size_t)N_;
    const int o = w * 1024 + l * 16;          // byte offset in Bs (one issue fills 8 KB)
    const int fr = o >> 6, jb = (o & 63) >> 1;

    for (int kt = 0; kt < 64; ++kt) {
        const int k0 = kt * 32;
        // B stage: 1x16B async per thread
        gload_lds16(ybase + (size_t)fr * N_ + k0 + jb, (char*)Bs + (w << 10));
        // A stage: 2 float4 per thread, cvt fp32->bf16 in-reg
#pragma unroll
        for (int q = 0; q < 2; ++q) {
            const int idx = t + 512 * q;      // float4 index 0..1023
            const int row = idx >> 3, jq = idx & 7;
            const float4 v = *(const float4*)(abase + (size_t)row * N_ + k0 + jq * 4);
            const uint32_t u0 = (uint32_t)f2bf(v.x) | ((uint32_t)f2bf(v.y) << 16);
            const uint32_t u1 = (uint32_t)f2bf(v.z) | ((uint32_t)f2bf(v.w) << 16);
            *(uint2*)&As[row * 32 + jq * 4] = make_uint2(u0, u1);
        }
        __syncthreads();                      // drains vmcnt (gload_lds) + lgkm (ds_write)
        bf16x8 af[4], bfr[2];
#pragma unroll
        for (int mi = 0; mi < 4; ++mi)
            af[mi] = *(const bf16x8*)&As[(wr * 64 + mi * 16 + (l & 15)) * 32 + (l >> 4) * 8];
#pragma unroll
        for (int ni = 0; ni < 2; ++ni)
            bfr[ni] = *(const bf16x8*)&Bs[(wc * 32 + ni * 16 + (l & 15)) * 32 + (l >> 4) * 8];
#pragma unroll
        for (int mi = 0; mi < 4; ++mi)
#pragma unroll
            for (int ni = 0; ni < 2; ++ni)
                acc[mi][ni] = __builtin_amdgcn_mfma_f32_16x16x32_bf16(af[mi], bfr[ni], acc[mi][ni], 0, 0, 0);
        __syncthreads();
    }
    // epilogue: z = bf16(s_out * t). C/D: col=lane&15, row=(lane>>4)*4+reg
#pragma unroll
    for (int mi = 0; mi < 4; ++mi) {
#pragma unroll
        for (int r = 0; r < 4; ++r) {
            const int row = i0 + wr * 64 + mi * 16 + (l >> 4) * 4 + r;
            const float d = deg_col[(size_t)b * N_ + row];
            const float so = (d != 0.f) ? rsqrtf(d) : 0.f;
#pragma unroll
            for (int ni = 0; ni < 2; ++ni) {
                const int col = f0 + wc * 32 + ni * 16 + (l & 15);
                z[((size_t)b * N_ + row) * F_ + col] = f2bf(so * acc[mi][ni][r]);
            }
        }
    }
}

// ---------------------------------------------------------------------------
// K4: out = softplus( xn @ (Ws+Wn) + z @ (-Wn) )  — virtual K=512 GEMM.
// Same tile geometry as K3; both A and B via global_load_lds.
// ---------------------------------------------------------------------------
__global__ __launch_bounds__(512) void k_gemm2(const u16* __restrict__ xn,
                                               const u16* __restrict__ z,
                                               const u16* __restrict__ WcT,
                                               const u16* __restrict__ WnT,
                                               float* __restrict__ out) {
    const int i = blockIdx.x;
    const int g = i & 7, s = i >> 3;
    const int mt = g * 16 + (s & 15);         // 0..127 (16384 rows / 128)
    const int nt = s >> 4;
    const int r0 = mt * 128, o0 = nt * 128;
    const int t = threadIdx.x, w = t >> 6, l = t & 63;
    const int wr = w >> 2, wc = w & 3;
    alignas(16) __shared__ u16 As[128 * 32];
    alignas(16) __shared__ u16 Bs[128 * 32];
    f32x4 acc[4][2];
#pragma unroll
    for (int mi = 0; mi < 4; ++mi)
#pragma unroll
        for (int ni = 0; ni < 2; ++ni) acc[mi][ni] = (f32x4)0.f;

    const int o = w * 1024 + l * 16;
    const int row = o >> 6, cb = (o & 63) >> 1;

    for (int kt = 0; kt < 16; ++kt) {
        const u16* asrc = (kt < 8) ? xn : z;
        const u16* bsrc = (kt < 8) ? WcT : WnT;
        const int kk0 = (kt & 7) * 32;
        gload_lds16(asrc + (size_t)(r0 + row) * F_ + kk0 + cb, (char*)As + (w << 10));
        gload_lds16(bsrc + (size_t)(o0 + row) * F_ + kk0 + cb, (char*)Bs + (w << 10));
        __syncthreads();
        bf16x8 af[4], bfr[2];
#pragma unroll
        for (int mi = 0; mi < 4; ++mi)
            af[mi] = *(const bf16x8*)&As[(wr * 64 + mi * 16 + (l & 15)) * 32 + (l >> 4) * 8];
#pragma unroll
        for (int ni = 0; ni < 2; ++ni)
            bfr[ni] = *(const bf16x8*)&Bs[(wc * 32 + ni * 16 + (l & 15)) * 32 + (l >> 4) * 8];
#pragma unroll
        for (int mi = 0; mi < 4; ++mi)
#pragma unroll
            for (int ni = 0; ni < 2; ++ni)
                acc[mi][ni] = __builtin_amdgcn_mfma_f32_16x16x32_bf16(af[mi], bfr[ni], acc[mi][ni], 0, 0, 0);
        __syncthreads();
    }
#pragma unroll
    for (int mi = 0; mi < 4; ++mi) {
#pragma unroll
        for (int r = 0; r < 4; ++r) {
            const int rr = r0 + wr * 64 + mi * 16 + (l >> 4) * 4 + r;
#pragma unroll
            for (int ni = 0; ni < 2; ++ni) {
                const int cc = o0 + wc * 32 + ni * 16 + (l & 15);
                const float p = acc[mi][ni][r];
                out[(size_t)rr * F_ + cc] = (p > 20.f) ? p : log1pf(expf(p));
            }
        }
    }
}

// ---------------------------------------------------------------------------
extern "C" void kernel_launch(void* const* d_in, const int* in_sizes, int n_in,
                              void* d_out, int out_size, void* d_ws, size_t ws_size,
                              hipStream_t stream) {
    (void)in_sizes; (void)n_in; (void)out_size; (void)ws_size;
    const float* x     = (const float*)d_in[0];
    const float* adj   = (const float*)d_in[1];
    const float* gamma = (const float*)d_in[2];
    const float* beta  = (const float*)d_in[3];
    const float* Ws    = (const float*)d_in[4];
    const float* Wn    = (const float*)d_in[5];
    float* out = (float*)d_out;

    char* ws = (char*)d_ws;
    float* deg_row = (float*)(ws + 0);                        //  64 KB
    float* deg_col = (float*)(ws + 65536);                    //  64 KB
    u16* xn  = (u16*)(ws + 131072);                           // 8.0 MB
    u16* yT  = (u16*)(ws + 131072 + 8388608);                 // 8.0 MB
    u16* z   = (u16*)(ws + 131072 + 2 * 8388608);             // 8.0 MB
    u16* WcT = (u16*)(ws + 131072 + 3 * 8388608);             // 128 KB
    u16* WnT = (u16*)(ws + 131072 + 3 * 8388608 + 131072);    // 128 KB  (total ~24.4 MB)

    hipMemsetAsync(ws, 0, 131072, stream);  // zero degree accumulators
    k_deg  <<<dim3(128, 8), 256, 0, stream>>>(adj, deg_row, deg_col);
    k_wprep<<<256, 256, 0, stream>>>(Ws, Wn, WcT, WnT);
    k_ln   <<<dim3(64, 8), 256, 0, stream>>>(x, gamma, beta, deg_row, xn, yT);
    k_gemm1<<<256, 512, 0, stream>>>(adj, yT, deg_col, z);
    k_gemm2<<<256, 512, 0, stream>>>(xn, z, WcT, WnT, out);
}

// Round 2
// 323.474 us; speedup vs baseline: 1.1718x; 1.1718x over previous
//
#include <hip/hip_runtime.h>
#include <stdint.h>

#define B_ 8
#define N_ 2048
#define F_ 256

typedef unsigned short u16;
typedef __attribute__((ext_vector_type(8))) short bf16x8;   // 8 bf16 in 4 VGPRs
typedef __attribute__((ext_vector_type(4))) float f32x4;

// round-to-nearest-even f32 -> bf16
__device__ __forceinline__ u16 f2bf(float f) {
    uint32_t u = __builtin_bit_cast(uint32_t, f);
    u += 0x7FFFu + ((u >> 16) & 1u);
    return (u16)(u >> 16);
}

// async global->LDS, 16B per lane. LDS dest = wave-uniform base + lane*16.
__device__ __forceinline__ void gload_lds16(const void* g, void* lds_uniform_base) {
    __builtin_amdgcn_global_load_lds(
        (const __attribute__((address_space(1))) uint32_t*)g,
        (__attribute__((address_space(3))) uint32_t*)lds_uniform_base, 16, 0, 0);
}

// ---------------------------------------------------------------------------
// K1: degrees, NO atomics. 32-row panels. deg_row written complete (full-width
// row sums). Column sums written as per-panel partials pcol[b][panel][j];
// k_dcol reduces the 64 partials. Thread t owns cols {t*4..t*4+3, 1024+t*4..+3}.
// ---------------------------------------------------------------------------
__global__ __launch_bounds__(256) void k_deg(const float* __restrict__ adj,
                                             float* __restrict__ deg_row,
                                             float* __restrict__ pcol) {
    const int b = blockIdx.y, panel = blockIdx.x;      // 64 panels x 32 rows
    const int t = threadIdx.x, w = t >> 6, l = t & 63;
    const float* base = adj + ((size_t)b * N_ + (size_t)panel * 32) * N_;
    float c0[4], c1[4];
#pragma unroll
    for (int e = 0; e < 4; ++e) { c0[e] = 0.f; c1[e] = 0.f; }
    __shared__ float rs[32][4];
#pragma unroll 4
    for (int r = 0; r < 32; ++r) {
        const float4 v0 = *(const float4*)(base + (size_t)r * N_ + t * 4);
        const float4 v1 = *(const float4*)(base + (size_t)r * N_ + 1024 + t * 4);
        c0[0] += v0.x; c0[1] += v0.y; c0[2] += v0.z; c0[3] += v0.w;
        c1[0] += v1.x; c1[1] += v1.y; c1[2] += v1.z; c1[3] += v1.w;
        float s = (v0.x + v0.y) + (v0.z + v0.w) + (v1.x + v1.y) + (v1.z + v1.w);
#pragma unroll
        for (int off = 32; off; off >>= 1) s += __shfl_xor(s, off);
        if (l == 0) rs[r][w] = s;
    }
    float4* pc = (float4*)(pcol + ((size_t)(b * 64 + panel)) * N_);
    pc[t]       = make_float4(c0[0], c0[1], c0[2], c0[3]);
    pc[t + 256] = make_float4(c1[0], c1[1], c1[2], c1[3]);
    __syncthreads();
    if (t < 32)
        deg_row[(size_t)b * N_ + panel * 32 + t] = rs[t][0] + rs[t][1] + rs[t][2] + rs[t][3];
}

// Reduce the 64 per-panel partials -> deg_col (raw column sums).
__global__ __launch_bounds__(256) void k_dcol(const float* __restrict__ pcol,
                                              float* __restrict__ deg_col) {
    const int tid = blockIdx.x * 256 + threadIdx.x;    // 16384 = 8 * 2048
    const int b = tid >> 11, j = tid & 2047;
    const float* p = pcol + (size_t)b * 64 * N_ + j;
    float s = 0.f;
#pragma unroll
    for (int g = 0; g < 64; ++g) s += p[(size_t)g * N_];
    deg_col[tid] = s;
}

// ---------------------------------------------------------------------------
// K2: LayerNorm -> xn (bf16 row-major [b][n][f]) and yT (bf16 [b][f][n]).
// 32-row panels; wave w handles 8 rows; transpose via padded LDS tile.
// ---------------------------------------------------------------------------
__global__ __launch_bounds__(256) void k_ln(const float* __restrict__ x,
                                            const float* __restrict__ gamma,
                                            const float* __restrict__ beta,
                                            const float* __restrict__ deg_row,
                                            u16* __restrict__ xn,
                                            u16* __restrict__ yT) {
    const int b = blockIdx.y, panel = blockIdx.x;      // 64 panels x 32 rows
    const int t = threadIdx.x, w = t >> 6, l = t & 63;
    __shared__ u16 yt[256 * 34];                       // [f][jj], pad 34 -> 2-way banks (free)
    float g[4], be[4];
#pragma unroll
    for (int m = 0; m < 4; ++m) { g[m] = gamma[l + 64 * m]; be[m] = beta[l + 64 * m]; }
    for (int rr = 0; rr < 8; ++rr) {
        const int jj = w * 8 + rr;
        const int j = panel * 32 + jj;
        const float* xp = x + ((size_t)b * N_ + j) * F_;
        float v[4], s = 0.f, ss = 0.f;
#pragma unroll
        for (int m = 0; m < 4; ++m) { v[m] = xp[l + 64 * m]; s += v[m]; ss += v[m] * v[m]; }
#pragma unroll
        for (int off = 32; off; off >>= 1) { s += __shfl_xor(s, off); ss += __shfl_xor(ss, off); }
        const float mu = s * (1.f / 256.f);
        const float var = ss * (1.f / 256.f) - mu * mu;
        const float rstd = rsqrtf(var + 1e-5f);
        const float d = deg_row[(size_t)b * N_ + j];
        const float sin_ = (d != 0.f) ? rsqrtf(d) : 0.f;
        u16* xnp = xn + ((size_t)b * N_ + j) * F_;
#pragma unroll
        for (int m = 0; m < 4; ++m) {
            const float xv = (v[m] - mu) * rstd * g[m] + be[m];
            xnp[l + 64 * m] = f2bf(xv);
            yt[(l + 64 * m) * 34 + jj] = f2bf(sin_ * xv);
        }
    }
    __syncthreads();
    // write yT: thread t -> f = (t>>1)+128*m2, 16-j chunk (t&1)
#pragma unroll
    for (int m2 = 0; m2 < 2; ++m2) {
        const int f = (t >> 1) + 128 * m2;
        const int jj0 = (t & 1) * 16;
        uint32_t vals[8];
#pragma unroll
        for (int e = 0; e < 8; ++e) vals[e] = *(const uint32_t*)&yt[f * 34 + jj0 + 2 * e];
        uint4* dst = (uint4*)(yT + ((size_t)b * F_ + f) * N_ + panel * 32 + jj0);
        dst[0] = make_uint4(vals[0], vals[1], vals[2], vals[3]);
        dst[1] = make_uint4(vals[4], vals[5], vals[6], vals[7]);
    }
}

// ---------------------------------------------------------------------------
// Kw: WcT[o][k] = bf16(Ws[k][o] + Wn[k][o]); WnT[o][k] = bf16(-Wn[k][o])
// ---------------------------------------------------------------------------
__global__ __launch_bounds__(256) void k_wprep(const float* __restrict__ Ws,
                                               const float* __restrict__ Wn,
                                               u16* __restrict__ WcT,
                                               u16* __restrict__ WnT) {
    const int k = blockIdx.x, o = threadIdx.x;
    const float a = Ws[k * 256 + o], q = Wn[k * 256 + o];
    WcT[o * 256 + k] = f2bf(a + q);
    WnT[o * 256 + k] = f2bf(-q);
}

// ---------------------------------------------------------------------------
// K3: z[b,i,f] = bf16( s_out[b,i] * sum_j adj[b,i,j] * yT[b,f,j] )
// 128x128 tile, BK=32, 512 threads (8 waves: 2 row x 4 col, each 64x32).
// A: fp32 reg-staged + cvt; B: global_load_lds width 16.
// Block map: b = blk&7 (one batch per XCD, B panel L2-resident);
// nt fastest within XCD so the (m, nt=0/1) pair sharing an A-panel is
// dispatch-adjacent -> A fetched from HBM once, partner hits L2.
// ---------------------------------------------------------------------------
__global__ __launch_bounds__(512) void k_gemm1(const float* __restrict__ adj,
                                               const u16* __restrict__ yT,
                                               const float* __restrict__ deg_col,
                                               u16* __restrict__ z) {
    const int i = blockIdx.x;                 // 256 blocks
    const int b = i & 7;
    const int kk = i >> 3;                    // 0..31 within XCD
    const int nt = kk & 1;
    const int m = kk >> 1;                    // 0..15
    const int i0 = m * 128, f0 = nt * 128;
    const int t = threadIdx.x, w = t >> 6, l = t & 63;
    const int wr = w >> 2, wc = w & 3;        // wave -> 64x32 subtile
    alignas(16) __shared__ u16 As[128 * 32];  // [i][k] 8 KB
    alignas(16) __shared__ u16 Bs[128 * 32];  // [f][k] 8 KB
    f32x4 acc[4][2];
#pragma unroll
    for (int mi = 0; mi < 4; ++mi)
#pragma unroll
        for (int ni = 0; ni < 2; ++ni) acc[mi][ni] = (f32x4)0.f;

    const float* abase = adj + ((size_t)b * N_ + i0) * N_;
    const u16* ybase = yT + ((size_t)b * F_ + f0) * (size_t)N_;
    const int o = w * 1024 + l * 16;          // byte offset in Bs (one issue fills 8 KB)
    const int fr = o >> 6, jb = (o & 63) >> 1;

    for (int kt = 0; kt < 64; ++kt) {
        const int k0 = kt * 32;
        // B stage: 1x16B async per thread
        gload_lds16(ybase + (size_t)fr * N_ + k0 + jb, (char*)Bs + (w << 10));
        // A stage: 2 float4 per thread, cvt fp32->bf16 in-reg
#pragma unroll
        for (int q = 0; q < 2; ++q) {
            const int idx = t + 512 * q;      // float4 index 0..1023
            const int row = idx >> 3, jq = idx & 7;
            const float4 v = *(const float4*)(abase + (size_t)row * N_ + k0 + jq * 4);
            const uint32_t u0 = (uint32_t)f2bf(v.x) | ((uint32_t)f2bf(v.y) << 16);
            const uint32_t u1 = (uint32_t)f2bf(v.z) | ((uint32_t)f2bf(v.w) << 16);
            *(uint2*)&As[row * 32 + jq * 4] = make_uint2(u0, u1);
        }
        __syncthreads();                      // drains vmcnt (gload_lds) + lgkm (ds_write)
        bf16x8 af[4], bfr[2];
#pragma unroll
        for (int mi = 0; mi < 4; ++mi)
            af[mi] = *(const bf16x8*)&As[(wr * 64 + mi * 16 + (l & 15)) * 32 + (l >> 4) * 8];
#pragma unroll
        for (int ni = 0; ni < 2; ++ni)
            bfr[ni] = *(const bf16x8*)&Bs[(wc * 32 + ni * 16 + (l & 15)) * 32 + (l >> 4) * 8];
#pragma unroll
        for (int mi = 0; mi < 4; ++mi)
#pragma unroll
            for (int ni = 0; ni < 2; ++ni)
                acc[mi][ni] = __builtin_amdgcn_mfma_f32_16x16x32_bf16(af[mi], bfr[ni], acc[mi][ni], 0, 0, 0);
        __syncthreads();
    }
    // epilogue: z = bf16(s_out * t). C/D: col=lane&15, row=(lane>>4)*4+reg
#pragma unroll
    for (int mi = 0; mi < 4; ++mi) {
#pragma unroll
        for (int r = 0; r < 4; ++r) {
            const int row = i0 + wr * 64 + mi * 16 + (l >> 4) * 4 + r;
            const float d = deg_col[(size_t)b * N_ + row];
            const float so = (d != 0.f) ? rsqrtf(d) : 0.f;
#pragma unroll
            for (int ni = 0; ni < 2; ++ni) {
                const int col = f0 + wc * 32 + ni * 16 + (l & 15);
                z[((size_t)b * N_ + row) * F_ + col] = f2bf(so * acc[mi][ni][r]);
            }
        }
    }
}

// ---------------------------------------------------------------------------
// K4: out = softplus( xn @ (Ws+Wn) + z @ (-Wn) )  — virtual K=512 GEMM.
// Same tile geometry as K3; both A and B via global_load_lds.
// nt fastest within XCD so the (mt, nt=0/1) pair sharing A-tiles is adjacent.
// ---------------------------------------------------------------------------
__global__ __launch_bounds__(512) void k_gemm2(const u16* __restrict__ xn,
                                               const u16* __restrict__ z,
                                               const u16* __restrict__ WcT,
                                               const u16* __restrict__ WnT,
                                               float* __restrict__ out) {
    const int i = blockIdx.x;
    const int xcd = i & 7;
    const int kk = i >> 3;                    // 0..31
    const int nt = kk & 1;
    const int mt = xcd + 8 * (kk >> 1);       // 0..127
    const int r0 = mt * 128, o0 = nt * 128;
    const int t = threadIdx.x, w = t >> 6, l = t & 63;
    const int wr = w >> 2, wc = w & 3;
    alignas(16) __shared__ u16 As[128 * 32];
    alignas(16) __shared__ u16 Bs[128 * 32];
    f32x4 acc[4][2];
#pragma unroll
    for (int mi = 0; mi < 4; ++mi)
#pragma unroll
        for (int ni = 0; ni < 2; ++ni) acc[mi][ni] = (f32x4)0.f;

    const int o = w * 1024 + l * 16;
    const int row = o >> 6, cb = (o & 63) >> 1;

    for (int kt = 0; kt < 16; ++kt) {
        const u16* asrc = (kt < 8) ? xn : z;
        const u16* bsrc = (kt < 8) ? WcT : WnT;
        const int kk0 = (kt & 7) * 32;
        gload_lds16(asrc + (size_t)(r0 + row) * F_ + kk0 + cb, (char*)As + (w << 10));
        gload_lds16(bsrc + (size_t)(o0 + row) * F_ + kk0 + cb, (char*)Bs + (w << 10));
        __syncthreads();
        bf16x8 af[4], bfr[2];
#pragma unroll
        for (int mi = 0; mi < 4; ++mi)
            af[mi] = *(const bf16x8*)&As[(wr * 64 + mi * 16 + (l & 15)) * 32 + (l >> 4) * 8];
#pragma unroll
        for (int ni = 0; ni < 2; ++ni)
            bfr[ni] = *(const bf16x8*)&Bs[(wc * 32 + ni * 16 + (l & 15)) * 32 + (l >> 4) * 8];
#pragma unroll
        for (int mi = 0; mi < 4; ++mi)
#pragma unroll
            for (int ni = 0; ni < 2; ++ni)
                acc[mi][ni] = __builtin_amdgcn_mfma_f32_16x16x32_bf16(af[mi], bfr[ni], acc[mi][ni], 0, 0, 0);
        __syncthreads();
    }
#pragma unroll
    for (int mi = 0; mi < 4; ++mi) {
#pragma unroll
        for (int r = 0; r < 4; ++r) {
            const int rr = r0 + wr * 64 + mi * 16 + (l >> 4) * 4 + r;
#pragma unroll
            for (int ni = 0; ni < 2; ++ni) {
                const int cc = o0 + wc * 32 + ni * 16 + (l & 15);
                const float p = acc[mi][ni][r];
                out[(size_t)rr * F_ + cc] = (p > 20.f) ? p : log1pf(expf(p));
            }
        }
    }
}

// ---------------------------------------------------------------------------
extern "C" void kernel_launch(void* const* d_in, const int* in_sizes, int n_in,
                              void* d_out, int out_size, void* d_ws, size_t ws_size,
                              hipStream_t stream) {
    (void)in_sizes; (void)n_in; (void)out_size; (void)ws_size;
    const float* x     = (const float*)d_in[0];
    const float* adj   = (const float*)d_in[1];
    const float* gamma = (const float*)d_in[2];
    const float* beta  = (const float*)d_in[3];
    const float* Ws    = (const float*)d_in[4];
    const float* Wn    = (const float*)d_in[5];
    float* out = (float*)d_out;

    char* ws = (char*)d_ws;
    float* deg_row = (float*)(ws + 0);                        //  64 KB
    float* deg_col = (float*)(ws + 65536);                    //  64 KB
    u16* xn  = (u16*)(ws + 131072);                           // 8.0 MB
    u16* yT  = (u16*)(ws + 131072 + 8388608);                 // 8.0 MB
    u16* z   = (u16*)(ws + 131072 + 2 * 8388608);             // 8.0 MB
    u16* WcT = (u16*)(ws + 131072 + 3 * 8388608);             // 128 KB
    u16* WnT = (u16*)(ws + 131072 + 3 * 8388608 + 131072);    // 128 KB  (total ~24.4 MB)
    // pcol (4 MB of per-panel column partials) aliases the z region: it is
    // fully consumed by k_dcol before k_gemm1 writes z.
    float* pcol = (float*)z;

    k_deg  <<<dim3(64, 8), 256, 0, stream>>>(adj, deg_row, pcol);
    k_dcol <<<64, 256, 0, stream>>>(pcol, deg_col);
    k_wprep<<<256, 256, 0, stream>>>(Ws, Wn, WcT, WnT);
    k_ln   <<<dim3(64, 8), 256, 0, stream>>>(x, gamma, beta, deg_row, xn, yT);
    k_gemm1<<<256, 512, 0, stream>>>(adj, yT, deg_col, z);
    k_gemm2<<<256, 512, 0, stream>>>(xn, z, WcT, WnT, out);
}

// Round 3
// 322.629 us; speedup vs baseline: 1.1749x; 1.0026x over previous
//
#include <hip/hip_runtime.h>
#include <stdint.h>

#define B_ 8
#define N_ 2048
#define F_ 256

typedef unsigned short u16;
typedef __attribute__((ext_vector_type(8))) short bf16x8;   // 8 bf16 in 4 VGPRs
typedef __attribute__((ext_vector_type(4))) float f32x4;

// round-to-nearest-even f32 -> bf16
__device__ __forceinline__ u16 f2bf(float f) {
    uint32_t u = __builtin_bit_cast(uint32_t, f);
    u += 0x7FFFu + ((u >> 16) & 1u);
    return (u16)(u >> 16);
}

// async global->LDS, 16B per lane. LDS dest = wave-uniform base + lane*16.
__device__ __forceinline__ void gload_lds16(const void* g, void* lds_uniform_base) {
    __builtin_amdgcn_global_load_lds(
        (const __attribute__((address_space(1))) uint32_t*)g,
        (__attribute__((address_space(3))) uint32_t*)lds_uniform_base, 16, 0, 0);
}

// ---------------------------------------------------------------------------
// K1: degrees, NO atomics. 32-row panels. deg_row written complete; column
// sums written as per-panel partials pcol[b][panel][j] (reduced in k_mid).
// ---------------------------------------------------------------------------
__global__ __launch_bounds__(256) void k_deg(const float* __restrict__ adj,
                                             float* __restrict__ deg_row,
                                             float* __restrict__ pcol) {
    const int b = blockIdx.y, panel = blockIdx.x;      // 64 panels x 32 rows
    const int t = threadIdx.x, w = t >> 6, l = t & 63;
    const float* base = adj + ((size_t)b * N_ + (size_t)panel * 32) * N_;
    float c0[4], c1[4];
#pragma unroll
    for (int e = 0; e < 4; ++e) { c0[e] = 0.f; c1[e] = 0.f; }
    __shared__ float rs[32][4];
#pragma unroll 4
    for (int r = 0; r < 32; ++r) {
        const float4 v0 = *(const float4*)(base + (size_t)r * N_ + t * 4);
        const float4 v1 = *(const float4*)(base + (size_t)r * N_ + 1024 + t * 4);
        c0[0] += v0.x; c0[1] += v0.y; c0[2] += v0.z; c0[3] += v0.w;
        c1[0] += v1.x; c1[1] += v1.y; c1[2] += v1.z; c1[3] += v1.w;
        float s = (v0.x + v0.y) + (v0.z + v0.w) + (v1.x + v1.y) + (v1.z + v1.w);
#pragma unroll
        for (int off = 32; off; off >>= 1) s += __shfl_xor(s, off);
        if (l == 0) rs[r][w] = s;
    }
    float4* pc = (float4*)(pcol + ((size_t)(b * 64 + panel)) * N_);
    pc[t]       = make_float4(c0[0], c0[1], c0[2], c0[3]);
    pc[t + 256] = make_float4(c1[0], c1[1], c1[2], c1[3]);
    __syncthreads();
    if (t < 32)
        deg_row[(size_t)b * N_ + panel * 32 + t] = rs[t][0] + rs[t][1] + rs[t][2] + rs[t][3];
}

// ---------------------------------------------------------------------------
// K2 (fused): role by blockIdx.x:
//   [0,512)   LayerNorm -> xn (row-major) + yT ([b][f][n] via LDS transpose)
//   [512,576) reduce pcol partials -> deg_col
//   [576,584) weight prep: WcT = (Ws+Wn)^T, WnT = (-Wn)^T, bf16
// ---------------------------------------------------------------------------
__global__ __launch_bounds__(256) void k_mid(const float* __restrict__ x,
                                             const float* __restrict__ gamma,
                                             const float* __restrict__ beta,
                                             const float* __restrict__ deg_row,
                                             const float* __restrict__ pcol,
                                             const float* __restrict__ Ws,
                                             const float* __restrict__ Wn,
                                             u16* __restrict__ xn,
                                             u16* __restrict__ yT,
                                             float* __restrict__ deg_col,
                                             u16* __restrict__ WcT,
                                             u16* __restrict__ WnT) {
    const int bx = blockIdx.x;
    const int t = threadIdx.x;
    __shared__ u16 yt[256 * 34];                       // [f][jj], pad 34
    if (bx < 512) {                                    // ---- LayerNorm role
        const int b = bx >> 6, panel = bx & 63;
        const int w = t >> 6, l = t & 63;
        float g[4], be[4];
#pragma unroll
        for (int m = 0; m < 4; ++m) { g[m] = gamma[l + 64 * m]; be[m] = beta[l + 64 * m]; }
        for (int rr = 0; rr < 8; ++rr) {
            const int jj = w * 8 + rr;
            const int j = panel * 32 + jj;
            const float* xp = x + ((size_t)b * N_ + j) * F_;
            float v[4], s = 0.f, ss = 0.f;
#pragma unroll
            for (int m = 0; m < 4; ++m) { v[m] = xp[l + 64 * m]; s += v[m]; ss += v[m] * v[m]; }
#pragma unroll
            for (int off = 32; off; off >>= 1) { s += __shfl_xor(s, off); ss += __shfl_xor(ss, off); }
            const float mu = s * (1.f / 256.f);
            const float var = ss * (1.f / 256.f) - mu * mu;
            const float rstd = rsqrtf(var + 1e-5f);
            const float d = deg_row[(size_t)b * N_ + j];
            const float sin_ = (d != 0.f) ? rsqrtf(d) : 0.f;
            u16* xnp = xn + ((size_t)b * N_ + j) * F_;
#pragma unroll
            for (int m = 0; m < 4; ++m) {
                const float xv = (v[m] - mu) * rstd * g[m] + be[m];
                xnp[l + 64 * m] = f2bf(xv);
                yt[(l + 64 * m) * 34 + jj] = f2bf(sin_ * xv);
            }
        }
        __syncthreads();
#pragma unroll
        for (int m2 = 0; m2 < 2; ++m2) {
            const int f = (t >> 1) + 128 * m2;
            const int jj0 = (t & 1) * 16;
            uint32_t vals[8];
#pragma unroll
            for (int e = 0; e < 8; ++e) vals[e] = *(const uint32_t*)&yt[f * 34 + jj0 + 2 * e];
            uint4* dst = (uint4*)(yT + ((size_t)b * F_ + f) * N_ + panel * 32 + jj0);
            dst[0] = make_uint4(vals[0], vals[1], vals[2], vals[3]);
            dst[1] = make_uint4(vals[4], vals[5], vals[6], vals[7]);
        }
    } else if (bx < 576) {                             // ---- deg_col reduce role
        const int tid = (bx - 512) * 256 + t;          // 16384 = 8 * 2048
        const int b = tid >> 11, j = tid & 2047;
        const float* p = pcol + (size_t)b * 64 * N_ + j;
        float s = 0.f;
#pragma unroll
        for (int g = 0; g < 64; ++g) s += p[(size_t)g * N_];
        deg_col[tid] = s;
    } else {                                           // ---- weight prep role
        const int rel = bx - 576;
#pragma unroll 4
        for (int e = 0; e < 32; ++e) {
            const int idx = rel * 8192 + e * 256 + t;  // idx = k*256 + o
            const int k = idx >> 8, o = idx & 255;
            const float a = Ws[idx], q = Wn[idx];
            WcT[o * 256 + k] = f2bf(a + q);
            WnT[o * 256 + k] = f2bf(-q);
        }
    }
}

// ---------------------------------------------------------------------------
// K3: z[b,i,f] = bf16( s_out[b,i] * sum_j adj[b,i,j] * yT[b,f,j] )
// 64x256 tile (adj read from HBM exactly once), BK=32, 512 threads
// (8 waves: 2 row x 4 col, each 32x64). Double-buffered 2-phase pipeline:
// issue A-regs + B gload_lds for t+1, MFMA on t, cvt+ds_write, ONE barrier.
// b = blk&7 keeps one batch per XCD (yT stays L2-resident).
// ---------------------------------------------------------------------------
__global__ __launch_bounds__(512) void k_gemm1(const float* __restrict__ adj,
                                               const u16* __restrict__ yT,
                                               const float* __restrict__ deg_col,
                                               u16* __restrict__ z) {
    const int blk = blockIdx.x;               // 256 blocks
    const int b = blk & 7;
    const int m = blk >> 3;                   // 0..31
    const int i0 = m * 64;
    const int t = threadIdx.x, w = t >> 6, l = t & 63;
    const int wr = w >> 2, wc = w & 3;        // wave -> 32x64 subtile
    alignas(16) __shared__ u16 As[2][64 * 32];   // 4 KB each
    alignas(16) __shared__ u16 Bs[2][256 * 32];  // 16 KB each
    f32x4 acc[2][4];
#pragma unroll
    for (int mi = 0; mi < 2; ++mi)
#pragma unroll
        for (int ni = 0; ni < 4; ++ni) acc[mi][ni] = (f32x4)0.f;

    const float* abase = adj + ((size_t)b * N_ + i0) * N_;
    const u16* ybase = yT + (size_t)b * F_ * (size_t)N_;
    const int ar = t >> 3, aj = t & 7;        // A stage: 1 float4/thread
    const int o = w * 1024 + l * 16;          // B stage: byte offset of issue 1
    const int fr = o >> 6, jb = (o & 63) >> 1;

    // prologue: tile 0
    {
        const float4 av = *(const float4*)(abase + (size_t)ar * N_ + aj * 4);
        gload_lds16(ybase + (size_t)fr * N_ + jb, (char*)&Bs[0][0] + (w << 10));
        gload_lds16(ybase + (size_t)(fr + 128) * N_ + jb, (char*)&Bs[0][0] + 8192 + (w << 10));
        const uint32_t u0 = (uint32_t)f2bf(av.x) | ((uint32_t)f2bf(av.y) << 16);
        const uint32_t u1 = (uint32_t)f2bf(av.z) | ((uint32_t)f2bf(av.w) << 16);
        *(uint2*)&As[0][ar * 32 + aj * 4] = make_uint2(u0, u1);
    }
    __syncthreads();

    for (int kt = 0; kt < 64; ++kt) {
        const int cb = kt & 1, nb = cb ^ 1;
        float4 an;
        if (kt < 63) {                        // issue next tile's loads FIRST
            const int k0 = (kt + 1) * 32;
            an = *(const float4*)(abase + (size_t)ar * N_ + k0 + aj * 4);
            gload_lds16(ybase + (size_t)fr * N_ + k0 + jb, (char*)&Bs[nb][0] + (w << 10));
            gload_lds16(ybase + (size_t)(fr + 128) * N_ + k0 + jb, (char*)&Bs[nb][0] + 8192 + (w << 10));
        }
        bf16x8 af[2], bfr[4];
#pragma unroll
        for (int mi = 0; mi < 2; ++mi)
            af[mi] = *(const bf16x8*)&As[cb][(wr * 32 + mi * 16 + (l & 15)) * 32 + (l >> 4) * 8];
#pragma unroll
        for (int ni = 0; ni < 4; ++ni)
            bfr[ni] = *(const bf16x8*)&Bs[cb][(wc * 64 + ni * 16 + (l & 15)) * 32 + (l >> 4) * 8];
#pragma unroll
        for (int mi = 0; mi < 2; ++mi)
#pragma unroll
            for (int ni = 0; ni < 4; ++ni)
                acc[mi][ni] = __builtin_amdgcn_mfma_f32_16x16x32_bf16(af[mi], bfr[ni], acc[mi][ni], 0, 0, 0);
        if (kt < 63) {                        // cvt arrives after MFMA hid the latency
            const uint32_t u0 = (uint32_t)f2bf(an.x) | ((uint32_t)f2bf(an.y) << 16);
            const uint32_t u1 = (uint32_t)f2bf(an.z) | ((uint32_t)f2bf(an.w) << 16);
            *(uint2*)&As[nb][ar * 32 + aj * 4] = make_uint2(u0, u1);
        }
        __syncthreads();
    }
    // epilogue: z = bf16(s_out * acc). C/D: col=lane&15, row=(lane>>4)*4+reg
#pragma unroll
    for (int mi = 0; mi < 2; ++mi) {
#pragma unroll
        for (int r = 0; r < 4; ++r) {
            const int row = i0 + wr * 32 + mi * 16 + (l >> 4) * 4 + r;
            const float d = deg_col[(size_t)b * N_ + row];
            const float so = (d != 0.f) ? rsqrtf(d) : 0.f;
#pragma unroll
            for (int ni = 0; ni < 4; ++ni) {
                const int col = wc * 64 + ni * 16 + (l & 15);
                z[((size_t)b * N_ + row) * F_ + col] = f2bf(so * acc[mi][ni][r]);
            }
        }
    }
}

// ---------------------------------------------------------------------------
// K4: out = softplus( xn @ (Ws+Wn) + z @ (-Wn) ) — virtual K=512 GEMM.
// 128x128 tile, double-buffered 2-phase pipeline, both operands gload_lds.
// ---------------------------------------------------------------------------
__global__ __launch_bounds__(512) void k_gemm2(const u16* __restrict__ xn,
                                               const u16* __restrict__ z,
                                               const u16* __restrict__ WcT,
                                               const u16* __restrict__ WnT,
                                               float* __restrict__ out) {
    const int i = blockIdx.x;
    const int xcd = i & 7;
    const int kk = i >> 3;                    // 0..31
    const int nt = kk & 1;
    const int mt = xcd + 8 * (kk >> 1);       // 0..127
    const int r0 = mt * 128, o0 = nt * 128;
    const int t = threadIdx.x, w = t >> 6, l = t & 63;
    const int wr = w >> 2, wc = w & 3;
    alignas(16) __shared__ u16 As[2][128 * 32];
    alignas(16) __shared__ u16 Bs[2][128 * 32];
    f32x4 acc[4][2];
#pragma unroll
    for (int mi = 0; mi < 4; ++mi)
#pragma unroll
        for (int ni = 0; ni < 2; ++ni) acc[mi][ni] = (f32x4)0.f;

    const int o = w * 1024 + l * 16;
    const int row = o >> 6, cb2 = (o & 63) >> 1;

    // prologue: tile 0 (kt=0 -> xn / WcT, kk0=0)
    gload_lds16(xn + (size_t)(r0 + row) * F_ + cb2, (char*)&As[0][0] + (w << 10));
    gload_lds16(WcT + (size_t)(o0 + row) * F_ + cb2, (char*)&Bs[0][0] + (w << 10));
    __syncthreads();

    for (int kt = 0; kt < 16; ++kt) {
        const int cb = kt & 1, nb = cb ^ 1;
        if (kt < 15) {
            const int kn = kt + 1;
            const u16* asrc = (kn < 8) ? xn : z;
            const u16* bsrc = (kn < 8) ? WcT : WnT;
            const int kk0 = (kn & 7) * 32;
            gload_lds16(asrc + (size_t)(r0 + row) * F_ + kk0 + cb2, (char*)&As[nb][0] + (w << 10));
            gload_lds16(bsrc + (size_t)(o0 + row) * F_ + kk0 + cb2, (char*)&Bs[nb][0] + (w << 10));
        }
        bf16x8 af[4], bfr[2];
#pragma unroll
        for (int mi = 0; mi < 4; ++mi)
            af[mi] = *(const bf16x8*)&As[cb][(wr * 64 + mi * 16 + (l & 15)) * 32 + (l >> 4) * 8];
#pragma unroll
        for (int ni = 0; ni < 2; ++ni)
            bfr[ni] = *(const bf16x8*)&Bs[cb][(wc * 32 + ni * 16 + (l & 15)) * 32 + (l >> 4) * 8];
#pragma unroll
        for (int mi = 0; mi < 4; ++mi)
#pragma unroll
            for (int ni = 0; ni < 2; ++ni)
                acc[mi][ni] = __builtin_amdgcn_mfma_f32_16x16x32_bf16(af[mi], bfr[ni], acc[mi][ni], 0, 0, 0);
        __syncthreads();
    }
#pragma unroll
    for (int mi = 0; mi < 4; ++mi) {
#pragma unroll
        for (int r = 0; r < 4; ++r) {
            const int rr = r0 + wr * 64 + mi * 16 + (l >> 4) * 4 + r;
#pragma unroll
            for (int ni = 0; ni < 2; ++ni) {
                const int cc = o0 + wc * 32 + ni * 16 + (l & 15);
                const float p = acc[mi][ni][r];
                out[(size_t)rr * F_ + cc] = (p > 20.f) ? p : log1pf(expf(p));
            }
        }
    }
}

// ---------------------------------------------------------------------------
extern "C" void kernel_launch(void* const* d_in, const int* in_sizes, int n_in,
                              void* d_out, int out_size, void* d_ws, size_t ws_size,
                              hipStream_t stream) {
    (void)in_sizes; (void)n_in; (void)out_size; (void)ws_size;
    const float* x     = (const float*)d_in[0];
    const float* adj   = (const float*)d_in[1];
    const float* gamma = (const float*)d_in[2];
    const float* beta  = (const float*)d_in[3];
    const float* Ws    = (const float*)d_in[4];
    const float* Wn    = (const float*)d_in[5];
    float* out = (float*)d_out;

    char* ws = (char*)d_ws;
    float* deg_row = (float*)(ws + 0);                        //  64 KB
    float* deg_col = (float*)(ws + 65536);                    //  64 KB
    u16* xn  = (u16*)(ws + 131072);                           // 8.0 MB
    u16* yT  = (u16*)(ws + 131072 + 8388608);                 // 8.0 MB
    u16* z   = (u16*)(ws + 131072 + 2 * 8388608);             // 8.0 MB
    u16* WcT = (u16*)(ws + 131072 + 3 * 8388608);             // 128 KB
    u16* WnT = (u16*)(ws + 131072 + 3 * 8388608 + 131072);    // 128 KB  (total ~24.4 MB)
    // pcol (4 MB of per-panel column partials) aliases the z region: it is
    // fully consumed by k_mid's reduce role before k_gemm1 writes z.
    float* pcol = (float*)z;

    k_deg  <<<dim3(64, 8), 256, 0, stream>>>(adj, deg_row, pcol);
    k_mid  <<<584, 256, 0, stream>>>(x, gamma, beta, deg_row, pcol, Ws, Wn,
                                     xn, yT, deg_col, WcT, WnT);
    k_gemm1<<<256, 512, 0, stream>>>(adj, yT, deg_col, z);
    k_gemm2<<<256, 512, 0, stream>>>(xn, z, WcT, WnT, out);
}

// Round 4
// 303.703 us; speedup vs baseline: 1.2481x; 1.0623x over previous
//
#include <hip/hip_runtime.h>
#include <stdint.h>

#define B_ 8
#define N_ 2048
#define F_ 256

typedef unsigned short u16;
typedef __attribute__((ext_vector_type(8))) short bf16x8;   // 8 bf16 in 4 VGPRs
typedef __attribute__((ext_vector_type(4))) float f32x4;

// round-to-nearest-even f32 -> bf16
__device__ __forceinline__ u16 f2bf(float f) {
    uint32_t u = __builtin_bit_cast(uint32_t, f);
    u += 0x7FFFu + ((u >> 16) & 1u);
    return (u16)(u >> 16);
}
__device__ __forceinline__ uint32_t pack2(float a, float b) {
    return (uint32_t)f2bf(a) | ((uint32_t)f2bf(b) << 16);
}

// async global->LDS, 16B per lane. LDS dest must be wave-uniform base; HW adds lane*16.
__device__ __forceinline__ void gload_lds16(const void* g, void* lds_uniform_base) {
    __builtin_amdgcn_global_load_lds(
        (const __attribute__((address_space(1))) uint32_t*)g,
        (__attribute__((address_space(3))) uint32_t*)lds_uniform_base, 16, 0, 0);
}

// ---------------------------------------------------------------------------
// K1 (k_pre): single pass over adj panel (32 rows):
//   - row sums (complete, in-block) -> s_in
//   - per-panel column partials pcol[b][panel][j] (no atomics)
//   - adj_bf = bf16(adj)  (so gemm1 reads 67 MB not 134 MB, pure gload_lds)
//   - LayerNorm of the same 32 rows -> xn (row-major) + yT ([b][f][n], s_in folded)
// 512 blocks x 256 thr = 2 blocks/CU.
// ---------------------------------------------------------------------------
__global__ __launch_bounds__(256) void k_pre(const float* __restrict__ adj,
                                             const float* __restrict__ x,
                                             const float* __restrict__ gamma,
                                             const float* __restrict__ beta,
                                             u16* __restrict__ adj_bf,
                                             float* __restrict__ pcol,
                                             u16* __restrict__ xn,
                                             u16* __restrict__ yT) {
    const int b = blockIdx.y, panel = blockIdx.x;      // 64 panels x 32 rows
    const int t = threadIdx.x, w = t >> 6, l = t & 63;
    __shared__ float rs[32][4];
    __shared__ u16 yt[256 * 34];                       // [f][jj], pad 34
    const float* base = adj + ((size_t)b * N_ + (size_t)panel * 32) * N_;
    u16* abf = adj_bf + ((size_t)b * N_ + (size_t)panel * 32) * N_;
    float c0[4], c1[4];
#pragma unroll
    for (int e = 0; e < 4; ++e) { c0[e] = 0.f; c1[e] = 0.f; }
#pragma unroll 4
    for (int r = 0; r < 32; ++r) {
        const float4 v0 = *(const float4*)(base + (size_t)r * N_ + t * 4);
        const float4 v1 = *(const float4*)(base + (size_t)r * N_ + 1024 + t * 4);
        c0[0] += v0.x; c0[1] += v0.y; c0[2] += v0.z; c0[3] += v0.w;
        c1[0] += v1.x; c1[1] += v1.y; c1[2] += v1.z; c1[3] += v1.w;
        *(uint2*)&abf[(size_t)r * N_ + t * 4] = make_uint2(pack2(v0.x, v0.y), pack2(v0.z, v0.w));
        *(uint2*)&abf[(size_t)r * N_ + 1024 + t * 4] = make_uint2(pack2(v1.x, v1.y), pack2(v1.z, v1.w));
        float s = (v0.x + v0.y) + (v0.z + v0.w) + (v1.x + v1.y) + (v1.z + v1.w);
#pragma unroll
        for (int off = 32; off; off >>= 1) s += __shfl_xor(s, off);
        if (l == 0) rs[r][w] = s;
    }
    float4* pc = (float4*)(pcol + ((size_t)(b * 64 + panel)) * N_);
    pc[t]       = make_float4(c0[0], c0[1], c0[2], c0[3]);
    pc[t + 256] = make_float4(c1[0], c1[1], c1[2], c1[3]);
    __syncthreads();
    // ---- LayerNorm for this panel's 32 rows (s_in from in-block row sums)
    float g[4], be[4];
#pragma unroll
    for (int m = 0; m < 4; ++m) { g[m] = gamma[l + 64 * m]; be[m] = beta[l + 64 * m]; }
    for (int rr = 0; rr < 8; ++rr) {
        const int jj = w * 8 + rr;
        const int j = panel * 32 + jj;
        const float rowsum = rs[jj][0] + rs[jj][1] + rs[jj][2] + rs[jj][3];
        const float sin_ = (rowsum != 0.f) ? rsqrtf(rowsum) : 0.f;
        const float* xp = x + ((size_t)b * N_ + j) * F_;
        float v[4], s = 0.f, ss = 0.f;
#pragma unroll
        for (int m = 0; m < 4; ++m) { v[m] = xp[l + 64 * m]; s += v[m]; ss += v[m] * v[m]; }
#pragma unroll
        for (int off = 32; off; off >>= 1) { s += __shfl_xor(s, off); ss += __shfl_xor(ss, off); }
        const float mu = s * (1.f / 256.f);
        const float var = ss * (1.f / 256.f) - mu * mu;
        const float rstd = rsqrtf(var + 1e-5f);
        u16* xnp = xn + ((size_t)b * N_ + j) * F_;
#pragma unroll
        for (int m = 0; m < 4; ++m) {
            const float xv = (v[m] - mu) * rstd * g[m] + be[m];
            xnp[l + 64 * m] = f2bf(xv);
            yt[(l + 64 * m) * 34 + jj] = f2bf(sin_ * xv);
        }
    }
    __syncthreads();
    // write yT stripes: thread t -> f = (t>>1)+128*m2, 16-j chunk (t&1)
#pragma unroll
    for (int m2 = 0; m2 < 2; ++m2) {
        const int f = (t >> 1) + 128 * m2;
        const int jj0 = (t & 1) * 16;
        uint32_t vals[8];
#pragma unroll
        for (int e = 0; e < 8; ++e) vals[e] = *(const uint32_t*)&yt[f * 34 + jj0 + 2 * e];
        uint4* dst = (uint4*)(yT + ((size_t)b * F_ + f) * N_ + panel * 32 + jj0);
        dst[0] = make_uint4(vals[0], vals[1], vals[2], vals[3]);
        dst[1] = make_uint4(vals[4], vals[5], vals[6], vals[7]);
    }
}

// ---------------------------------------------------------------------------
// K2 (k_mid): bx<64: reduce pcol partials -> deg_col; bx in [64,72): weight prep.
// ---------------------------------------------------------------------------
__global__ __launch_bounds__(256) void k_mid(const float* __restrict__ pcol,
                                             const float* __restrict__ Ws,
                                             const float* __restrict__ Wn,
                                             float* __restrict__ deg_col,
                                             u16* __restrict__ WcT,
                                             u16* __restrict__ WnT) {
    const int bx = blockIdx.x, t = threadIdx.x;
    if (bx < 64) {
        const int tid = bx * 256 + t;                  // 16384 = 8 * 2048
        const int b = tid >> 11, j = tid & 2047;
        const float* p = pcol + (size_t)b * 64 * N_ + j;
        float s = 0.f;
#pragma unroll
        for (int g = 0; g < 64; ++g) s += p[(size_t)g * N_];
        deg_col[tid] = s;
    } else {
        const int rel = bx - 64;
#pragma unroll 4
        for (int e = 0; e < 32; ++e) {
            const int idx = rel * 8192 + e * 256 + t;  // idx = k*256 + o
            const int k = idx >> 8, o = idx & 255;
            const float a = Ws[idx], q = Wn[idx];
            WcT[o * 256 + k] = f2bf(a + q);
            WnT[o * 256 + k] = f2bf(-q);
        }
    }
}

// ---------------------------------------------------------------------------
// K3 (k_gemm1): z[b,i,f] = bf16( s_out[b,i] * sum_j adj_bf[b,i,j] * yT[b,f,j] )
// m97 structure: 256 thr / 4 waves, 64x128 tile, BK=32, single-buffered
// 2-barrier loop, A+B both gload_lds. Grid 512 = 2 blocks/CU (cross-block
// overlap fills the barrier drain). b = blk&7: batch pinned to one XCD
// (yT[b] 1MB L2-resident); nt pairs sharing an A-panel dispatch-adjacent.
// ---------------------------------------------------------------------------
__global__ __launch_bounds__(256) void k_gemm1(const u16* __restrict__ adj_bf,
                                               const u16* __restrict__ yT,
                                               const float* __restrict__ deg_col,
                                               u16* __restrict__ z) {
    const int blk = blockIdx.x;               // 512 blocks
    const int b = blk & 7;
    const int kk = blk >> 3;                  // 0..63
    const int nt = kk & 1;
    const int m = kk >> 1;                    // 0..31
    const int i0 = m * 64, f0 = nt * 128;
    const int t = threadIdx.x, w = t >> 6, l = t & 63;
    const int wr = w >> 1, wc = w & 1;        // wave -> 32x64 subtile
    alignas(16) __shared__ u16 As[64 * 32];   // 4 KB
    alignas(16) __shared__ u16 Bs[128 * 32];  // 8 KB
    f32x4 acc[2][4];
#pragma unroll
    for (int mi = 0; mi < 2; ++mi)
#pragma unroll
        for (int ni = 0; ni < 4; ++ni) acc[mi][ni] = (f32x4)0.f;

    const u16* abase = adj_bf + ((size_t)b * N_ + i0) * N_;
    const u16* ybase = yT + ((size_t)b * F_ + f0) * (size_t)N_;
    const int lr = l >> 2, lb = (l & 3) * 16; // lane -> row-in-16, byte-in-row

    for (int kt = 0; kt < 64; ++kt) {
        const int k0b = kt * 64;              // byte offset along k (32 bf16)
        // A: 64x32 bf16 = 4 KB, one issue (wave w covers rows w*16..+16)
        gload_lds16((const char*)(abase + (size_t)(w * 16 + lr) * N_) + k0b + lb,
                    (char*)As + (w << 10));
        // B: 128x32 bf16 = 8 KB, two issues
#pragma unroll
        for (int q = 0; q < 2; ++q)
            gload_lds16((const char*)(ybase + (size_t)(q * 64 + w * 16 + lr) * N_) + k0b + lb,
                        (char*)Bs + q * 4096 + (w << 10));
        __syncthreads();
        bf16x8 af[2], bfr[4];
#pragma unroll
        for (int mi = 0; mi < 2; ++mi)
            af[mi] = *(const bf16x8*)&As[(wr * 32 + mi * 16 + (l & 15)) * 32 + (l >> 4) * 8];
#pragma unroll
        for (int ni = 0; ni < 4; ++ni)
            bfr[ni] = *(const bf16x8*)&Bs[(wc * 64 + ni * 16 + (l & 15)) * 32 + (l >> 4) * 8];
#pragma unroll
        for (int mi = 0; mi < 2; ++mi)
#pragma unroll
            for (int ni = 0; ni < 4; ++ni)
                acc[mi][ni] = __builtin_amdgcn_mfma_f32_16x16x32_bf16(af[mi], bfr[ni], acc[mi][ni], 0, 0, 0);
        __syncthreads();
    }
    // epilogue: z = bf16(s_out * acc). C/D: col=lane&15, row=(lane>>4)*4+reg
#pragma unroll
    for (int mi = 0; mi < 2; ++mi) {
#pragma unroll
        for (int r = 0; r < 4; ++r) {
            const int row = i0 + wr * 32 + mi * 16 + (l >> 4) * 4 + r;
            const float d = deg_col[(size_t)b * N_ + row];
            const float so = (d != 0.f) ? rsqrtf(d) : 0.f;
#pragma unroll
            for (int ni = 0; ni < 4; ++ni) {
                const int col = f0 + wc * 64 + ni * 16 + (l & 15);
                z[((size_t)b * N_ + row) * F_ + col] = f2bf(so * acc[mi][ni][r]);
            }
        }
    }
}

// ---------------------------------------------------------------------------
// K4 (k_gemm2): out = softplus( xn @ (Ws+Wn) + z @ (-Wn) ) — virtual K=512.
// Same 64x128-tile / 256-thr structure; grid 512 = 2 blocks/CU.
// ---------------------------------------------------------------------------
__global__ __launch_bounds__(256) void k_gemm2(const u16* __restrict__ xn,
                                               const u16* __restrict__ z,
                                               const u16* __restrict__ WcT,
                                               const u16* __restrict__ WnT,
                                               float* __restrict__ out) {
    const int blk = blockIdx.x;               // 512 blocks
    const int xcd = blk & 7;
    const int kk = blk >> 3;                  // 0..63
    const int nt = kk & 1;
    const int mt = xcd + 8 * (kk >> 1);       // 0..255 (16384 rows / 64)
    const int r0 = mt * 64, o0 = nt * 128;
    const int t = threadIdx.x, w = t >> 6, l = t & 63;
    const int wr = w >> 1, wc = w & 1;
    alignas(16) __shared__ u16 As[64 * 32];
    alignas(16) __shared__ u16 Bs[128 * 32];
    f32x4 acc[2][4];
#pragma unroll
    for (int mi = 0; mi < 2; ++mi)
#pragma unroll
        for (int ni = 0; ni < 4; ++ni) acc[mi][ni] = (f32x4)0.f;

    const int lr = l >> 2, lb = (l & 3) * 16;

    for (int kt = 0; kt < 16; ++kt) {
        const u16* asrc = (kt < 8) ? xn : z;
        const u16* bsrc = (kt < 8) ? WcT : WnT;
        const int kk0b = (kt & 7) * 64;       // byte offset along k
        gload_lds16((const char*)(asrc + (size_t)(r0 + w * 16 + lr) * F_) + kk0b + lb,
                    (char*)As + (w << 10));
#pragma unroll
        for (int q = 0; q < 2; ++q)
            gload_lds16((const char*)(bsrc + (size_t)(o0 + q * 64 + w * 16 + lr) * F_) + kk0b + lb,
                        (char*)Bs + q * 4096 + (w << 10));
        __syncthreads();
        bf16x8 af[2], bfr[4];
#pragma unroll
        for (int mi = 0; mi < 2; ++mi)
            af[mi] = *(const bf16x8*)&As[(wr * 32 + mi * 16 + (l & 15)) * 32 + (l >> 4) * 8];
#pragma unroll
        for (int ni = 0; ni < 4; ++ni)
            bfr[ni] = *(const bf16x8*)&Bs[(wc * 64 + ni * 16 + (l & 15)) * 32 + (l >> 4) * 8];
#pragma unroll
        for (int mi = 0; mi < 2; ++mi)
#pragma unroll
            for (int ni = 0; ni < 4; ++ni)
                acc[mi][ni] = __builtin_amdgcn_mfma_f32_16x16x32_bf16(af[mi], bfr[ni], acc[mi][ni], 0, 0, 0);
        __syncthreads();
    }
#pragma unroll
    for (int mi = 0; mi < 2; ++mi) {
#pragma unroll
        for (int r = 0; r < 4; ++r) {
            const int rr = r0 + wr * 32 + mi * 16 + (l >> 4) * 4 + r;
#pragma unroll
            for (int ni = 0; ni < 4; ++ni) {
                const int cc = o0 + wc * 64 + ni * 16 + (l & 15);
                const float p = acc[mi][ni][r];
                out[(size_t)rr * F_ + cc] = (p > 20.f) ? p : log1pf(expf(p));
            }
        }
    }
}

// ---------------------------------------------------------------------------
extern "C" void kernel_launch(void* const* d_in, const int* in_sizes, int n_in,
                              void* d_out, int out_size, void* d_ws, size_t ws_size,
                              hipStream_t stream) {
    (void)in_sizes; (void)n_in; (void)out_size; (void)ws_size;
    const float* x     = (const float*)d_in[0];
    const float* adj   = (const float*)d_in[1];
    const float* gamma = (const float*)d_in[2];
    const float* beta  = (const float*)d_in[3];
    const float* Ws    = (const float*)d_in[4];
    const float* Wn    = (const float*)d_in[5];
    float* out = (float*)d_out;

    char* ws = (char*)d_ws;
    float* deg_col = (float*)(ws + 0);                 //  64 KB
    u16* xn     = (u16*)(ws + 65536);                  // 8.0 MB
    u16* yT     = (u16*)(ws + 8454144);                // 8.0 MB
    u16* z      = (u16*)(ws + 16842752);               // 8.0 MB
    u16* WcT    = (u16*)(ws + 25231360);               // 128 KB
    u16* WnT    = (u16*)(ws + 25362432);               // 128 KB
    u16* adj_bf = (u16*)(ws + 25493504);               // 67.1 MB (total ~92.6 MB)
    // pcol (4 MB of per-panel column partials) aliases the z region: fully
    // consumed by k_mid before k_gemm1 writes z.
    float* pcol = (float*)z;

    k_pre  <<<dim3(64, 8), 256, 0, stream>>>(adj, x, gamma, beta, adj_bf, pcol, xn, yT);
    k_mid  <<<72, 256, 0, stream>>>(pcol, Ws, Wn, deg_col, WcT, WnT);
    k_gemm1<<<512, 256, 0, stream>>>(adj_bf, yT, deg_col, z);
    k_gemm2<<<512, 256, 0, stream>>>(xn, z, WcT, WnT, out);
}